// Round 8
// baseline (119.375 us; speedup 1.0000x reference)
//
#include <hip/hip_runtime.h>
#include <hip/hip_bf16.h>
#include <math.h>

#define N_ROWS 32768
#define H      512
#define GV     640
#define V      320
#define DG     128
#define BM     64           // rows per block
#define NT     16           // K-steps of 32 (H=512)

typedef __attribute__((ext_vector_type(4))) float f32x4;
typedef __attribute__((ext_vector_type(8))) short short8v;   // 8 bf16

static __device__ __forceinline__ short f2bf(float f) {      // fp32 -> bf16 RNE
    unsigned int u = __float_as_uint(f);
    u += 0x7fffu + ((u >> 16) & 1u);
    return (short)(u >> 16);
}

// Pack W (fp32 [512][640]) into bf16 B-fragments for mfma_f32_16x16x32_bf16:
// frag (t, ct): lane l supplies B[k = t*32 + 8*(l>>4) + i][col = ct*16 + (l&15)], i=0..7.
// wp[(((t*40 + ct)*64 + l)*8 + i)] -> main-kernel B-load = 1 coalesced ushort8.
__global__ __launch_bounds__(256)
void pack_w(const float* __restrict__ W, short* __restrict__ wp)
{
    int gid = blockIdx.x * 256 + threadIdx.x;   // 40960 = 16 t * 40 ct * 64 l
    int l   = gid & 63;
    int ct  = (gid >> 6) % 40;
    int t   = gid / (40 * 64);
    int row = t * 32 + 8 * (l >> 4);
    int col = ct * 16 + (l & 15);
    short8v pk;
    #pragma unroll
    for (int i = 0; i < 8; ++i)
        pk[i] = f2bf(W[(size_t)(row + i) * GV + col]);
    *(short8v*)(wp + (size_t)gid * 8) = pk;
}

// Pack hidden (fp32 [32768][512]) into bf16 A-fragments, stored in the OUT buffer
// (33,554,432 B fits in out's 33,554,436 B; ordering vs out-writes is barrier-safe).
// frag (rt, t): lane l supplies A[row = rt*16 + (l&15)][k = t*32 + 8*(l>>4) + i], i=0..7.
// ap[((rt*16 + t)*64 + l)*8 + i] -> main-kernel A-load = 1 coalesced ushort8.
__global__ __launch_bounds__(256)
void pack_a(const float* __restrict__ hidden, short* __restrict__ ap)
{
    int gid = blockIdx.x * 256 + threadIdx.x;   // 2,097,152 = 2048 rt * 16 t * 64 l
    int l   = gid & 63;
    int t   = (gid >> 6) & 15;
    int rt  = gid >> 10;
    const float* src = hidden + (size_t)(rt * 16 + (l & 15)) * H + t * 32 + 8 * (l >> 4);
    float4 x0 = *(const float4*)src;
    float4 x1 = *(const float4*)(src + 4);
    short8v pk;
    pk[0] = f2bf(x0.x); pk[1] = f2bf(x0.y); pk[2] = f2bf(x0.z); pk[3] = f2bf(x0.w);
    pk[4] = f2bf(x1.x); pk[5] = f2bf(x1.y); pk[6] = f2bf(x1.z); pk[7] = f2bf(x1.w);
    *(short8v*)(ap + (size_t)gid * 8) = pk;
}

// Fused: bf16-MFMA logits GEMM + gumbel argmax + softmax marginal + codevector gather.
// 1024 threads = 16 waves, wave grid 4(M) x 4(N): wave (wm,wn) owns row-tile blockIdx*4+wm
// (16 rows) x cols wn*160..+159 (10 frags). acc[j] = f32x4: D[row=4q+r][col=cn].
// K-loop: pure ushort8 loads (A from apack, B from wpack) + MFMA. No LDS, no barriers,
// no converts -> short dependence chains; 16 waves/CU for latency hiding.
__global__ __launch_bounds__(1024, 4)
void gumbel_vq_main(const short* apack,               // aliases out! (no restrict)
                    const int*   __restrict__ mask,
                    const float* __restrict__ gumbel,
                    const short* __restrict__ wpack,
                    const float* __restrict__ bias,
                    const float* __restrict__ codevec,
                    float* out,                       // aliases apack (no restrict)
                    float* __restrict__ ws)
{
    __shared__ float smem[16 * 648];      // 16-row logits chunk (pad 640->648); reused as marg buf
    const int tid = threadIdx.x;
    const int tn  = tid & 63;
    const int wid = tid >> 6;             // 0..15
    const int wm  = wid >> 2, wn = wid & 3;
    const int q   = tn >> 4,  cn = tn & 15;
    const int row0 = blockIdx.x * BM;

    // acc init = bias (all 4 regs of a lane share the lane's column)
    f32x4 acc[10];
    #pragma unroll
    for (int j = 0; j < 10; ++j) {
        float b = bias[wn * 160 + j * 16 + cn];
        f32x4 c; c[0] = b; c[1] = b; c[2] = b; c[3] = b;
        acc[j] = c;
    }

    const short* ab = apack + ((size_t)(blockIdx.x * 4 + wm) * NT * 64 + tn) * 8;
    const short* bb = wpack + ((size_t)(wn * 10) * 64 + tn) * 8;

    #pragma unroll
    for (int t = 0; t < NT; ++t) {
        short8v a = *(const short8v*)(ab + (size_t)t * 512);
        #pragma unroll
        for (int j = 0; j < 10; ++j) {
            short8v bf = *(const short8v*)(bb + (size_t)t * 20480 + j * 512);
            acc[j] = __builtin_amdgcn_mfma_f32_16x16x32_bf16(a, bf, acc[j], 0, 0, 0);
        }
    }

    // ---- epilogue: 4 chunks of 16 rows; dump logits to LDS, then per-row code ----
    const int cA = 4 * tn;                // cols cA..cA+3 (group 0)
    const int cB = 256 + 4 * tn;          // cols cB..cB+3 (group 0 iff tn<16, lane-uniform)
    const int cC = 512 + 2 * tn;          // cols cC..cC+1 (group 1)
    const bool b_in1 = (tn >= 16);

    float marg[10];
    #pragma unroll
    for (int s = 0; s < 10; ++s) marg[s] = 0.f;

    #pragma unroll
    for (int c = 0; c < 4; ++c) {         // chunk c: block rows c*16..c*16+15 (owned by wm==c)
        __syncthreads();                  // chunk-0 barrier also orders apack reads before out writes
        if (wm == c) {
            #pragma unroll
            for (int j = 0; j < 10; ++j) {
                const int col = wn * 160 + j * 16 + cn;
                f32x4 v = acc[j];
                #pragma unroll
                for (int r = 0; r < 4; ++r)
                    smem[(4 * q + r) * 648 + col] = v[r];
            }
        }
        __syncthreads();

        // one row per wave
        const int row = row0 + c * 16 + wid;
        const float mrow = (mask[row] != 0) ? 1.f : 0.f;

        const float* lp = &smem[wid * 648];
        float4 aA = *(const float4*)(lp + cA);
        float4 aB = *(const float4*)(lp + cB);
        float2 aC = *(const float2*)(lp + cC);
        const float* gr = gumbel + (size_t)row * GV;
        float4 gA = *(const float4*)(gr + cA);
        float4 gB = *(const float4*)(gr + cB);
        float2 gC = *(const float2*)(gr + cC);

        float l0 = aA.x, l1 = aA.y, l2 = aA.z, l3 = aA.w;
        float l4 = aB.x, l5 = aB.y, l6 = aB.z, l7 = aB.w;
        float l8 = aC.x, l9 = aC.y;

        // chunk A (group 0)
        float z0 = l0 + gA.x, z1 = l1 + gA.y, z2 = l2 + gA.z, z3 = l3 + gA.w;
        float zm0 = z0; int zi0 = cA;
        if (z1 > zm0) { zm0 = z1; zi0 = cA + 1; }
        if (z2 > zm0) { zm0 = z2; zi0 = cA + 2; }
        if (z3 > zm0) { zm0 = z3; zi0 = cA + 3; }
        float lm0 = fmaxf(fmaxf(l0, l1), fmaxf(l2, l3));
        // chunk C (group 1)
        float z8 = l8 + gC.x, z9 = l9 + gC.y;
        float zm1 = z8; int zi1 = cC;
        if (z9 > zm1) { zm1 = z9; zi1 = cC + 1; }
        float lm1 = fmaxf(l8, l9);
        // chunk B (lane-uniform group)
        {
            float z4 = l4 + gB.x, z5 = l5 + gB.y, z6 = l6 + gB.z, z7 = l7 + gB.w;
            float zmB = z4; int ziB = cB;
            if (z5 > zmB) { zmB = z5; ziB = cB + 1; }
            if (z6 > zmB) { zmB = z6; ziB = cB + 2; }
            if (z7 > zmB) { zmB = z7; ziB = cB + 3; }
            float lmB = fmaxf(fmaxf(l4, l5), fmaxf(l6, l7));
            if (!b_in1) {
                if (zmB > zm0 || (zmB == zm0 && ziB < zi0)) { zm0 = zmB; zi0 = ziB; }
                lm0 = fmaxf(lm0, lmB);
            } else {
                if (zmB > zm1 || (zmB == zm1 && ziB < zi1)) { zm1 = zmB; zi1 = ziB; }
                lm1 = fmaxf(lm1, lmB);
            }
        }

        // 64-lane butterfly: argmax (first-index tie-break, matches jnp.argmax) + plain max
        #pragma unroll
        for (int d = 32; d >= 1; d >>= 1) {
            float oz; int oi;
            oz = __shfl_xor(zm0, d, 64); oi = __shfl_xor(zi0, d, 64);
            if (oz > zm0 || (oz == zm0 && oi < zi0)) { zm0 = oz; zi0 = oi; }
            oz = __shfl_xor(zm1, d, 64); oi = __shfl_xor(zi1, d, 64);
            if (oz > zm1 || (oz == zm1 && oi < zi1)) { zm1 = oz; zi1 = oi; }
            lm0 = fmaxf(lm0, __shfl_xor(lm0, d, 64));
            lm1 = fmaxf(lm1, __shfl_xor(lm1, d, 64));
        }

        // softmax(plain logits) per group -> masked marginal accumulation
        float lmB = b_in1 ? lm1 : lm0;
        float p0 = __expf(l0 - lm0), p1 = __expf(l1 - lm0), p2 = __expf(l2 - lm0), p3 = __expf(l3 - lm0);
        float p4 = __expf(l4 - lmB), p5 = __expf(l5 - lmB), p6 = __expf(l6 - lmB), p7 = __expf(l7 - lmB);
        float p8 = __expf(l8 - lm1), p9 = __expf(l9 - lm1);
        float pB = p4 + p5 + p6 + p7;
        float s0 = p0 + p1 + p2 + p3 + (b_in1 ? 0.f : pB);
        float s1 = p8 + p9 + (b_in1 ? pB : 0.f);
        #pragma unroll
        for (int d = 32; d >= 1; d >>= 1) {
            s0 += __shfl_xor(s0, d, 64);
            s1 += __shfl_xor(s1, d, 64);
        }
        float inv0 = mrow / s0, inv1 = mrow / s1;
        float invB = b_in1 ? inv1 : inv0;
        marg[0] += p0 * inv0; marg[1] += p1 * inv0; marg[2] += p2 * inv0; marg[3] += p3 * inv0;
        marg[4] += p4 * invB; marg[5] += p5 * invB; marg[6] += p6 * invB; marg[7] += p7 * invB;
        marg[8] += p8 * inv1; marg[9] += p9 * inv1;

        // codevector gather: lanes 0..31 write group 0's 128 floats, lanes 32..63 group 1
        int g   = tn >> 5;
        int idx = g ? (zi1 - V) : zi0;
        const float4* src = (const float4*)(codevec + ((size_t)g * V + idx) * DG);
        float4 vv = src[tn & 31];
        ((float4*)(out + (size_t)row * (2 * DG) + g * DG))[tn & 31] = vv;
    }

    // ---- cross-wave marginal reduce -> global atomics ----
    __syncthreads();                       // done with logits chunks; reuse smem as [16][640]
    float* mybuf = &smem[wid * GV];
    mybuf[cA] = marg[0]; mybuf[cA + 1] = marg[1]; mybuf[cA + 2] = marg[2]; mybuf[cA + 3] = marg[3];
    mybuf[cB] = marg[4]; mybuf[cB + 1] = marg[5]; mybuf[cB + 2] = marg[6]; mybuf[cB + 3] = marg[7];
    mybuf[cC] = marg[8]; mybuf[cC + 1] = marg[9];
    __syncthreads();
    if (tid < GV) {
        float s = 0.f;
        #pragma unroll
        for (int w = 0; w < 16; ++w) s += smem[w * GV + tid];
        atomicAdd(&ws[tid], s);
    }

    // mask count: wave 0 covers the block's 64 rows, one atomic per block
    if (wid == 0) {
        int mr = (mask[row0 + tn] != 0);
        unsigned long long b = __ballot(mr);
        if (tn == 0) atomicAdd(&ws[GV], (float)__popcll(b));
    }
}

__global__ void gumbel_vq_finalize(const float* __restrict__ ws, float* __restrict__ out)
{
    __shared__ float red[GV];
    int t = threadIdx.x;
    float cnt = ws[GV];
    float p = ws[t] / cnt;
    red[t] = p * logf(p + 1e-7f);
    __syncthreads();
    if (t == 0) {
        float e0 = 0.f, e1 = 0.f;
        for (int i = 0; i < V; ++i)  e0 += red[i];
        for (int i = V; i < GV; ++i) e1 += red[i];
        out[(size_t)N_ROWS * 2 * DG] = expf(-e0) + expf(-e1);
    }
}

extern "C" void kernel_launch(void* const* d_in, const int* in_sizes, int n_in,
                              void* d_out, int out_size, void* d_ws, size_t ws_size,
                              hipStream_t stream)
{
    const float* hidden  = (const float*)d_in[0];
    const int*   mask    = (const int*)  d_in[1];
    const float* gumbel  = (const float*)d_in[2];
    const float* W       = (const float*)d_in[3];
    const float* bias    = (const float*)d_in[4];
    const float* codevec = (const float*)d_in[5];
    float* out = (float*)d_out;
    float* ws  = (float*)d_ws;
    // ws layout: [0..639] marginal, [640] mask count, +4096B: W bf16 fragment pack (655 KB).
    // A bf16 fragment pack (33,554,432 B) lives in the OUT buffer (fits; barrier-ordered).
    short* wpack = (short*)((char*)d_ws + 4096);
    short* apack = (short*)d_out;

    hipMemsetAsync(d_ws, 0, (GV + 1) * sizeof(float), stream);
    pack_w<<<160, 256, 0, stream>>>(W, wpack);
    pack_a<<<8192, 256, 0, stream>>>(hidden, apack);
    gumbel_vq_main<<<N_ROWS / BM, 1024, 0, stream>>>(apack, mask, gumbel, wpack, bias, codevec, out, ws);
    gumbel_vq_finalize<<<1, GV, 0, stream>>>(ws, out);
}